// Round 1
// baseline (115.510 us; speedup 1.0000x reference)
//
#include <hip/hip_runtime.h>
#include <math.h>

#define BB 4096
#define HH 512
#define KK 32
#define PAIRS ((KK * (KK - 1)) / 2)   // 496

constexpr int TH  = 16;          // h-values per stage1 block
constexpr int NBB = 16;          // B-chunks
constexpr int BC  = BB / NBB;    // 256 rows per block
constexpr int SUB = 64;          // rows staged in LDS at a time

// ---------------------------------------------------------------------------
// Stage 1: class_sums (msum) = hidden^T @ cluster      [K,H] layout
//          S2 (s2sum)        = (hidden^2)^T @ cluster^2 [K,H] layout
//          colsum[k]         = sum_b cluster[b,k]
// ---------------------------------------------------------------------------
__global__ __launch_bounds__(256) void stage1_kernel(
    const float* __restrict__ hidden, const float* __restrict__ cluster,
    float* __restrict__ msum, float* __restrict__ s2sum,
    float* __restrict__ colsum)
{
    __shared__ float hid_s [SUB * TH];   // 1024 f
    __shared__ float hid2_s[SUB * TH];   // 1024 f
    __shared__ float clu_s [SUB * KK];   // 2048 f
    __shared__ float red   [8 * TH * KK];// 4096 f

    const int t  = threadIdx.x;
    const int ty = t >> 5;         // 0..7
    const int tx = t & 31;         // k index
    const int h0 = blockIdx.x * TH;
    const int bchunk = blockIdx.y * BC;

    float acc_m[TH], acc_s[TH];
#pragma unroll
    for (int i = 0; i < TH; ++i) { acc_m[i] = 0.f; acc_s[i] = 0.f; }
    float csum = 0.f;

    const float4* hid4 = (const float4*)hidden;
    const float4* clu4 = (const float4*)cluster;

    for (int sub = 0; sub < BC; sub += SUB) {
        const int b0 = bchunk + sub;
        // hidden tile: 64 rows x 16 cols = 256 float4, one per thread
        {
            int r = t >> 2, q = t & 3;
            float4 v = hid4[(size_t)(b0 + r) * (HH / 4) + (h0 >> 2) + q];
            ((float4*)hid_s)[t] = v;
            float4 v2; v2.x = v.x * v.x; v2.y = v.y * v.y;
            v2.z = v.z * v.z; v2.w = v.w * v.w;
            ((float4*)hid2_s)[t] = v2;
        }
        // cluster tile: 64 rows x 32 cols = 512 float4, two per thread
#pragma unroll
        for (int e = 0; e < 2; ++e) {
            int u = t + e * 256;
            int r = u >> 3, q = u & 7;
            ((float4*)clu_s)[u] = clu4[(size_t)(b0 + r) * (KK / 4) + q];
        }
        __syncthreads();

#pragma unroll
        for (int s = 0; s < SUB / 8; ++s) {
            int r = s * 8 + ty;
            float c  = clu_s[r * KK + tx];
            float c2 = c * c;
            csum += c;
#pragma unroll
            for (int hh = 0; hh < TH; ++hh) {
                acc_m[hh] = fmaf(hid_s [r * TH + hh], c,  acc_m[hh]);
                acc_s[hh] = fmaf(hid2_s[r * TH + hh], c2, acc_s[hh]);
            }
        }
        __syncthreads();
    }

    // counts accumulation: only one h-tile contributes (rows counted once)
    if (blockIdx.x == 0) atomicAdd(&colsum[tx], csum);

    // cross-group reduction for acc_m
#pragma unroll
    for (int hh = 0; hh < TH; ++hh) red[ty * (TH * KK) + hh * KK + tx] = acc_m[hh];
    __syncthreads();
    for (int u = t; u < TH * KK; u += 256) {
        float v = 0.f;
#pragma unroll
        for (int g = 0; g < 8; ++g) v += red[g * (TH * KK) + u];
        int hh = u >> 5, k = u & 31;
        atomicAdd(&msum[(size_t)k * HH + h0 + hh], v);
    }
    __syncthreads();
    // cross-group reduction for acc_s
#pragma unroll
    for (int hh = 0; hh < TH; ++hh) red[ty * (TH * KK) + hh * KK + tx] = acc_s[hh];
    __syncthreads();
    for (int u = t; u < TH * KK; u += 256) {
        float v = 0.f;
#pragma unroll
        for (int g = 0; g < 8; ++g) v += red[g * (TH * KK) + u];
        int hh = u >> 5, k = u & 31;
        atomicAdd(&s2sum[(size_t)k * HH + h0 + hh], v);
    }
}

// ---------------------------------------------------------------------------
// Continued fraction for incomplete beta (Numerical Recipes betacf, fp32)
// ---------------------------------------------------------------------------
__device__ float betacf_dev(float a, float b, float x)
{
    const float FPMIN = 1e-30f, EPS = 1e-6f;
    float qab = a + b, qap = a + 1.0f, qam = a - 1.0f;
    float c = 1.0f;
    float d = 1.0f - qab * x / qap;
    if (fabsf(d) < FPMIN) d = FPMIN;
    d = 1.0f / d;
    float h = d;
    for (int m = 1; m <= 200; ++m) {
        float m2 = 2.0f * (float)m;
        float aa = (float)m * (b - (float)m) * x / ((qam + m2) * (a + m2));
        d = 1.0f + aa * d; if (fabsf(d) < FPMIN) d = FPMIN;
        c = 1.0f + aa / c; if (fabsf(c) < FPMIN) c = FPMIN;
        d = 1.0f / d;
        h *= d * c;
        aa = -(a + (float)m) * (qab + (float)m) * x / ((a + m2) * (qap + m2));
        d = 1.0f + aa * d; if (fabsf(d) < FPMIN) d = FPMIN;
        c = 1.0f + aa / c; if (fabsf(c) < FPMIN) c = FPMIN;
        d = 1.0f / d;
        float del = d * c;
        h *= del;
        if (fabsf(del - 1.0f) < EPS) break;
    }
    return h;
}

// ---------------------------------------------------------------------------
// Stage 2: one block per class pair. Compute log(betainc) for all H, take
// top-d, sum logs, atomic accumulate -sum into out.
// ---------------------------------------------------------------------------
__global__ __launch_bounds__(256) void stage2_kernel(
    const float* __restrict__ msum, const float* __restrict__ s2sum,
    const float* __restrict__ colsum, const int* __restrict__ dptr,
    float* __restrict__ out)
{
    __shared__ float L[HH];
    __shared__ float rv[4];
    __shared__ int   ri[4];
    __shared__ float lg_s;

    const int t = threadIdx.x;
    const int p = blockIdx.x;

    // map pair index -> (i, j), row-major upper triangle (i<j)
    int i = 0, rem = p;
    while (true) { int row = KK - 1 - i; if (rem < row) break; rem -= row; ++i; }
    const int j = i + 1 + rem;

    const float ci = roundf(colsum[i]);
    const float cj = roundf(colsum[j]);
    const float pc = ci + cj;
    float d2 = pc - 2.0f;
    if (d2 == 0.0f) d2 = 1e-5f;
    const float a = 0.5f;
    const float b = 0.5f * d2;

    if (t == 0) {
        // lgamma(a+b) - lgamma(a) - lgamma(b), double precision (uniform)
        lg_s = (float)(lgamma((double)a + (double)b)
                       - 0.57236494292470008707   // lgamma(0.5) = ln(sqrt(pi))
                       - lgamma((double)b));
    }
    __syncthreads();
    const float lg = lg_s;
    const float xsplit = (a + 1.0f) / (a + b + 2.0f);

    for (int h = t; h < HH; h += 256) {
        float mi = msum[(size_t)i * HH + h];
        float mj = msum[(size_t)j * HH + h];
        float wi = fmaf((float)(BB - 2) * mi, mi, s2sum[(size_t)i * HH + h]);
        float wj = fmaf((float)(BB - 2) * mj, mj, s2sum[(size_t)j * HH + h]);
        float dm = 0.5f * (mi - mj);
        float between = dm * dm * pc;
        float pw = wi + wj;
        float denom = between + pw;
        float x   = between / denom;
        float omx = pw / denom;
        if (!(x >= 1e-37f)) { x = 1e-37f; omx = 1.0f; }          // low clip
        if (omx < 1e-5f)    { omx = 1e-5f; x = 1.0f - 1e-5f; }   // high clip

        float lbt = lg + a * logf(x) + b * logf(omx);
        float Lh;
        if (x < xsplit) {
            float cf = fmaxf(betacf_dev(a, b, x), 1e-30f);
            Lh = lbt + logf(2.0f * cf);          // log(bt*cf/a), a=0.5
        } else {
            float cf = fmaxf(betacf_dev(b, a, omx), 1e-30f);
            float tt = expf(lbt) * cf / b;       // 1 - I
            tt = fminf(tt, 0.9999999f);
            Lh = log1pf(-tt);
        }
        L[h] = Lh;
    }
    __syncthreads();

    const int d = *dptr;
    float ssum = 0.f;
    for (int r = 0; r < d; ++r) {
        float v = -INFINITY; int idx = 0;
        for (int h = t; h < HH; h += 256) {
            float lv = L[h];
            if (lv > v) { v = lv; idx = h; }
        }
#pragma unroll
        for (int off = 32; off > 0; off >>= 1) {
            float ov = __shfl_down(v, off);
            int   oi = __shfl_down(idx, off);
            if (ov > v) { v = ov; idx = oi; }
        }
        if ((t & 63) == 0) { rv[t >> 6] = v; ri[t >> 6] = idx; }
        __syncthreads();
        if (t == 0) {
            float bv = rv[0]; int bi = ri[0];
#pragma unroll
            for (int w = 1; w < 4; ++w)
                if (rv[w] > bv) { bv = rv[w]; bi = ri[w]; }
            ssum += bv;
            L[bi] = -INFINITY;
        }
        __syncthreads();
    }
    if (t == 0) atomicAdd(out, -ssum);
}

// ---------------------------------------------------------------------------
extern "C" void kernel_launch(void* const* d_in, const int* in_sizes, int n_in,
                              void* d_out, int out_size, void* d_ws, size_t ws_size,
                              hipStream_t stream)
{
    const float* hidden  = (const float*)d_in[0];
    const float* cluster = (const float*)d_in[1];
    const int*   dptr    = (const int*)d_in[2];

    float* msum   = (float*)d_ws;            // [K*H]
    float* s2sum  = msum + HH * KK;          // [K*H]
    float* colsum = s2sum + HH * KK;         // [K]

    size_t zbytes = (size_t)(2 * HH * KK + KK) * sizeof(float);
    hipMemsetAsync(d_ws, 0, zbytes, stream);
    hipMemsetAsync(d_out, 0, sizeof(float), stream);

    dim3 g1(HH / TH, NBB);
    stage1_kernel<<<g1, 256, 0, stream>>>(hidden, cluster, msum, s2sum, colsum);
    stage2_kernel<<<PAIRS, 256, 0, stream>>>(msum, s2sum, colsum, dptr,
                                             (float*)d_out);
}

// Round 2
// 102.801 us; speedup vs baseline: 1.1236x; 1.1236x over previous
//
#include <hip/hip_runtime.h>
#include <math.h>

#define BB 4096
#define HH 512
#define KK 32
#define PAIRS ((KK * (KK - 1)) / 2)   // 496

constexpr int TH  = 16;          // h-values per stage1 block
constexpr int NBB = 16;          // B-chunks
constexpr int BC  = BB / NBB;    // 256 rows per block
constexpr int SUB = 64;          // rows staged in LDS at a time

// ---------------------------------------------------------------------------
// Stage 1: msum  = hidden^T @ cluster        [K,H] layout
//          s2sum = (hidden^2)^T @ cluster^2  [K,H] layout  (squares in-reg)
//          colsum[k] = sum_b cluster[b,k]
// ---------------------------------------------------------------------------
__global__ __launch_bounds__(256) void stage1_kernel(
    const float* __restrict__ hidden, const float* __restrict__ cluster,
    float* __restrict__ msum, float* __restrict__ s2sum,
    float* __restrict__ colsum)
{
    __shared__ float hid_s [SUB * TH];   // 1024 f
    __shared__ float clu_s [SUB * KK];   // 2048 f
    __shared__ float red   [8 * TH * KK];// 4096 f

    const int t  = threadIdx.x;
    const int ty = t >> 5;         // 0..7
    const int tx = t & 31;         // k index
    const int h0 = blockIdx.x * TH;
    const int bchunk = blockIdx.y * BC;

    float acc_m[TH], acc_s[TH];
#pragma unroll
    for (int i = 0; i < TH; ++i) { acc_m[i] = 0.f; acc_s[i] = 0.f; }
    float csum = 0.f;

    const float4* hid4 = (const float4*)hidden;
    const float4* clu4 = (const float4*)cluster;

    for (int sub = 0; sub < BC; sub += SUB) {
        const int b0 = bchunk + sub;
        // hidden tile: 64 rows x 16 cols = 256 float4, one per thread
        {
            int r = t >> 2, q = t & 3;
            ((float4*)hid_s)[t] =
                hid4[(size_t)(b0 + r) * (HH / 4) + (h0 >> 2) + q];
        }
        // cluster tile: 64 rows x 32 cols = 512 float4, two per thread
#pragma unroll
        for (int e = 0; e < 2; ++e) {
            int u = t + e * 256;
            int r = u >> 3, q = u & 7;
            ((float4*)clu_s)[u] = clu4[(size_t)(b0 + r) * (KK / 4) + q];
        }
        __syncthreads();

#pragma unroll
        for (int s = 0; s < SUB / 8; ++s) {
            int r = s * 8 + ty;
            float c  = clu_s[r * KK + tx];
            float c2 = c * c;
            csum += c;
#pragma unroll
            for (int hh = 0; hh < TH; ++hh) {
                float hv = hid_s[r * TH + hh];
                acc_m[hh] = fmaf(hv,      c,  acc_m[hh]);
                acc_s[hh] = fmaf(hv * hv, c2, acc_s[hh]);
            }
        }
        __syncthreads();
    }

    if (blockIdx.x == 0) atomicAdd(&colsum[tx], csum);

#pragma unroll
    for (int hh = 0; hh < TH; ++hh) red[ty * (TH * KK) + hh * KK + tx] = acc_m[hh];
    __syncthreads();
    for (int u = t; u < TH * KK; u += 256) {
        float v = 0.f;
#pragma unroll
        for (int g = 0; g < 8; ++g) v += red[g * (TH * KK) + u];
        int hh = u >> 5, k = u & 31;
        atomicAdd(&msum[(size_t)k * HH + h0 + hh], v);
    }
    __syncthreads();
#pragma unroll
    for (int hh = 0; hh < TH; ++hh) red[ty * (TH * KK) + hh * KK + tx] = acc_s[hh];
    __syncthreads();
    for (int u = t; u < TH * KK; u += 256) {
        float v = 0.f;
#pragma unroll
        for (int g = 0; g < 8; ++g) v += red[g * (TH * KK) + u];
        int hh = u >> 5, k = u & 31;
        atomicAdd(&s2sum[(size_t)k * HH + h0 + hh], v);
    }
}

// ---------------------------------------------------------------------------
// Fast reciprocal (v_rcp_f32, ~1e-7 rel err)
// ---------------------------------------------------------------------------
__device__ __forceinline__ float frcp(float x) {
#if __has_builtin(__builtin_amdgcn_rcpf)
    return __builtin_amdgcn_rcpf(x);
#else
    return 1.0f / x;
#endif
}
__device__ __forceinline__ float guardf(float t) {
    return (fabsf(t) < 1e-30f) ? 1e-30f : t;
}

// Continued fraction (NR betacf), division-free inner loop, wave early-out.
// Called uniformly by all 64 lanes (per-lane a/b/x).
__device__ float betacf_fast(float a, float b, float x)
{
    const float EPS = 1e-5f;
    float qab = a + b, qap = a + 1.0f, qam = a - 1.0f;
    float c = 1.0f;
    float d = frcp(guardf(1.0f - qab * x * frcp(qap)));
    float h = d;
    for (int m = 1; m <= 100; ++m) {
        float fm = (float)m, m2 = 2.0f * fm;
        float aa = fm * (b - fm) * x * frcp((qam + m2) * (a + m2));
        d = frcp(guardf(fmaf(aa, d, 1.0f)));
        c = guardf(fmaf(aa, frcp(c), 1.0f));
        h *= d * c;
        float aa2 = -(a + fm) * (qab + fm) * x * frcp((a + m2) * (qap + m2));
        d = frcp(guardf(fmaf(aa2, d, 1.0f)));
        c = guardf(fmaf(aa2, frcp(c), 1.0f));
        float del = d * c;
        h *= del;
        if (__all(fabsf(del - 1.0f) < EPS)) break;
    }
    return h;
}

// ---------------------------------------------------------------------------
// Stage 2: one WAVE per pair. betainc(a,b,x) is monotone in x for fixed
// (a,b), and (a,b) is uniform within a pair -> top-d of betainc == top-d
// of x. Select top-d x via in-wave shuffles, then only d CF evaluations.
// ---------------------------------------------------------------------------
__global__ __launch_bounds__(64) void stage2_kernel(
    const float* __restrict__ msum, const float* __restrict__ s2sum,
    const float* __restrict__ colsum, const int* __restrict__ dptr,
    float* __restrict__ out)
{
    const int lane = threadIdx.x;
    const int p = blockIdx.x;

    // pair index -> (i, j), row-major upper triangle
    int i = 0, rem = p;
    while (true) { int row = KK - 1 - i; if (rem < row) break; rem -= row; ++i; }
    const int j = i + 1 + rem;

    const float ci = roundf(colsum[i]);
    const float cj = roundf(colsum[j]);
    const float pc = ci + cj;
    float d2 = pc - 2.0f;
    if (d2 == 0.0f) d2 = 1e-5f;
    const float a = 0.5f;
    const float b = 0.5f * d2;
    // lgamma(a+b)-lgamma(a)-lgamma(b); lgamma(0.5)=ln(sqrt(pi))
    const float lg = lgammaf(a + b) - lgammaf(b) - 0.57236494f;
    const float xsplit = (a + 1.0f) / (a + b + 2.0f);

    const float* mi_p = msum  + (size_t)i * HH;
    const float* mj_p = msum  + (size_t)j * HH;
    const float* si_p = s2sum + (size_t)i * HH;
    const float* sj_p = s2sum + (size_t)j * HH;

    float lv[8];
#pragma unroll
    for (int q = 0; q < 8; ++q) {
        int h = q * 64 + lane;
        float mi = mi_p[h], mj = mj_p[h];
        float wi = fmaf((float)(BB - 2) * mi, mi, si_p[h]);
        float wj = fmaf((float)(BB - 2) * mj, mj, sj_p[h]);
        float dm = 0.5f * (mi - mj);
        float between = dm * dm * pc;
        float denom = between + wi + wj;
        float x = between / denom;
        if (!(x >= 1e-37f)) x = 1e-37f;       // also catches NaN (denom==0)
        x = fminf(x, 1.0f - 1e-5f);
        lv[q] = x;
    }

    const int d = *dptr;

    // ---- top-d selection over 512 values (8/lane), value-only ----
    float myx = 0.004f;                        // safe filler for lanes >= d
    float lm = lv[0];
#pragma unroll
    for (int q = 1; q < 8; ++q) lm = fmaxf(lm, lv[q]);

    for (int r = 0; r < d; ++r) {
        float gm = lm;
#pragma unroll
        for (int off = 1; off < 64; off <<= 1)
            gm = fmaxf(gm, __shfl_xor(gm, off));
        unsigned long long msk = __ballot(lm == gm);
        int winner = __ffsll((unsigned long long)msk) - 1;
        if (lane == r) myx = gm;
        if (lane == winner) {
            bool done = false;
#pragma unroll
            for (int q = 0; q < 8; ++q)
                if (!done && lv[q] == gm) { lv[q] = -1.0f; done = true; }
            lm = lv[0];
#pragma unroll
            for (int q = 1; q < 8; ++q) lm = fmaxf(lm, lv[q]);
        }
    }

    // ---- d parallel betainc evals (all lanes run; lanes >= d discarded) ----
    float x   = myx;
    float omx = 1.0f - x;                      // x <= ~0.05 structurally
    bool  brA = x < xsplit;
    float al  = brA ? a : b;
    float be  = brA ? b : a;
    float xx  = brA ? x : omx;
    float cf  = betacf_fast(al, be, xx);
    float lbt = lg + 0.5f * logf(x) + b * logf(omx);
    float L;
    if (brA) {
        L = lbt + logf(2.0f * fmaxf(cf, 1e-30f));     // cf/a, a=0.5
    } else {
        float tt = expf(lbt) * cf / b;                 // 1 - I
        tt = fminf(tt, 0.99999988f);
        L = log1pf(-tt);
    }

    float val = (lane < d) ? L : 0.0f;
#pragma unroll
    for (int off = 1; off < 64; off <<= 1) val += __shfl_xor(val, off);
    if (lane == 0) atomicAdd(out, -val);
}

// ---------------------------------------------------------------------------
extern "C" void kernel_launch(void* const* d_in, const int* in_sizes, int n_in,
                              void* d_out, int out_size, void* d_ws, size_t ws_size,
                              hipStream_t stream)
{
    const float* hidden  = (const float*)d_in[0];
    const float* cluster = (const float*)d_in[1];
    const int*   dptr    = (const int*)d_in[2];

    float* msum   = (float*)d_ws;            // [K*H]
    float* s2sum  = msum + HH * KK;          // [K*H]
    float* colsum = s2sum + HH * KK;         // [K]

    size_t zbytes = (size_t)(2 * HH * KK + KK) * sizeof(float);
    hipMemsetAsync(d_ws, 0, zbytes, stream);
    hipMemsetAsync(d_out, 0, sizeof(float), stream);

    dim3 g1(HH / TH, NBB);
    stage1_kernel<<<g1, 256, 0, stream>>>(hidden, cluster, msum, s2sum, colsum);
    stage2_kernel<<<PAIRS, 64, 0, stream>>>(msum, s2sum, colsum, dptr,
                                            (float*)d_out);
}

// Round 3
// 95.349 us; speedup vs baseline: 1.2114x; 1.0782x over previous
//
#include <hip/hip_runtime.h>
#include <math.h>

#define BB 4096
#define HH 512
#define KK 32
#define PAIRS ((KK * (KK - 1)) / 2)   // 496

constexpr int TH  = 16;          // h-values per stage1 block
constexpr int NBB = 16;          // B-chunks
constexpr int BC  = BB / NBB;    // 256 rows per block
constexpr int SUB = 64;          // rows staged in LDS at a time
constexpr int RP  = TH + 1;      // padded reduce stride (17)

// ws layout (floats):
//   part_m [NBB][KK][HH] = 262144
//   part_s [NBB][KK][HH] = 262144
//   pcol   [NBB][KK]     = 512
//   ctl    [2]           = accum(float), counter(uint)

// ---------------------------------------------------------------------------
// Stage 1: per-chunk partial sums, NO atomics, NO zero-init required.
//   part_m[c][k][h] = sum_{b in chunk c} hidden[b,h]*cluster[b,k]
//   part_s[c][k][h] = sum_{b in chunk c} hidden^2 * cluster^2
//   pcol[c][k]      = sum_{b in chunk c} cluster[b,k]
// ---------------------------------------------------------------------------
__global__ __launch_bounds__(256) void stage1_kernel(
    const float* __restrict__ hidden, const float* __restrict__ cluster,
    float* __restrict__ part_m, float* __restrict__ part_s,
    float* __restrict__ pcol, float* __restrict__ ctl)
{
    __shared__ float hid_s[SUB * TH];      // 1024 f
    __shared__ float clu_s[SUB * KK];      // 2048 f
    __shared__ float red  [8 * KK * RP];   // 4352 f, +1 pad kills conflicts
    __shared__ float cred [8 * KK];        // 256 f

    const int t  = threadIdx.x;
    const int ty = t >> 5;         // 0..7
    const int tx = t & 31;         // k index
    const int h0 = blockIdx.x * TH;
    const int c  = blockIdx.y;
    const int bchunk = c * BC;

    if (blockIdx.x == 0 && c == 0 && t == 0) {
        ctl[0] = 0.0f;                     // accum
        ((unsigned*)ctl)[1] = 0u;          // counter
    }

    float acc_m[TH], acc_s[TH];
#pragma unroll
    for (int i = 0; i < TH; ++i) { acc_m[i] = 0.f; acc_s[i] = 0.f; }
    float csum = 0.f;

    const float4* hid4 = (const float4*)hidden;
    const float4* clu4 = (const float4*)cluster;

    for (int sub = 0; sub < BC; sub += SUB) {
        const int b0 = bchunk + sub;
        {   // hidden tile: 64 rows x 16 cols = 256 float4
            int r = t >> 2, q = t & 3;
            ((float4*)hid_s)[t] =
                hid4[(size_t)(b0 + r) * (HH / 4) + (h0 >> 2) + q];
        }
#pragma unroll
        for (int e = 0; e < 2; ++e) {      // cluster tile: 512 float4
            int u = t + e * 256;
            int r = u >> 3, q = u & 7;
            ((float4*)clu_s)[u] = clu4[(size_t)(b0 + r) * (KK / 4) + q];
        }
        __syncthreads();

#pragma unroll
        for (int s = 0; s < SUB / 8; ++s) {
            int r = s * 8 + ty;
            float cc = clu_s[r * KK + tx];
            float c2 = cc * cc;
            csum += cc;
#pragma unroll
            for (int hh = 0; hh < TH; ++hh) {
                float hv = hid_s[r * TH + hh];
                acc_m[hh] = fmaf(hv,      cc, acc_m[hh]);
                acc_s[hh] = fmaf(hv * hv, c2, acc_s[hh]);
            }
        }
        __syncthreads();
    }

    // colsum partial (chunk-local), reduce 8 ty-groups via LDS
    cred[ty * KK + tx] = csum;
    __syncthreads();
    if (blockIdx.x == 0 && t < KK) {
        float v = 0.f;
#pragma unroll
        for (int g = 0; g < 8; ++g) v += cred[g * KK + t];
        pcol[c * KK + t] = v;
    }

    // acc_m: cross-group reduce, store k-major (coalesced stage2 reads)
#pragma unroll
    for (int hh = 0; hh < TH; ++hh)
        red[ty * (KK * RP) + tx * RP + hh] = acc_m[hh];
    __syncthreads();
    for (int u = t; u < KK * TH; u += 256) {
        int k = u >> 4, hh = u & 15;
        float v = 0.f;
#pragma unroll
        for (int g = 0; g < 8; ++g) v += red[g * (KK * RP) + k * RP + hh];
        part_m[((size_t)c * KK + k) * HH + h0 + hh] = v;
    }
    __syncthreads();
#pragma unroll
    for (int hh = 0; hh < TH; ++hh)
        red[ty * (KK * RP) + tx * RP + hh] = acc_s[hh];
    __syncthreads();
    for (int u = t; u < KK * TH; u += 256) {
        int k = u >> 4, hh = u & 15;
        float v = 0.f;
#pragma unroll
        for (int g = 0; g < 8; ++g) v += red[g * (KK * RP) + k * RP + hh];
        part_s[((size_t)c * KK + k) * HH + h0 + hh] = v;
    }
}

// ---------------------------------------------------------------------------
__device__ __forceinline__ float frcp(float x) {
#if __has_builtin(__builtin_amdgcn_rcpf)
    return __builtin_amdgcn_rcpf(x);
#else
    return 1.0f / x;
#endif
}
__device__ __forceinline__ float guardf(float t) {
    return (fabsf(t) < 1e-30f) ? 1e-30f : t;
}

// NR betacf, division-free (v_rcp_f32), wave early-out.
__device__ float betacf_fast(float a, float b, float x)
{
    const float EPS = 1e-5f;
    float qab = a + b, qap = a + 1.0f, qam = a - 1.0f;
    float c = 1.0f;
    float d = frcp(guardf(1.0f - qab * x * frcp(qap)));
    float h = d;
    for (int m = 1; m <= 100; ++m) {
        float fm = (float)m, m2 = 2.0f * fm;
        float aa = fm * (b - fm) * x * frcp((qam + m2) * (a + m2));
        d = frcp(guardf(fmaf(aa, d, 1.0f)));
        c = guardf(fmaf(aa, frcp(c), 1.0f));
        h *= d * c;
        float aa2 = -(a + fm) * (qab + fm) * x * frcp((a + m2) * (qap + m2));
        d = frcp(guardf(fmaf(aa2, d, 1.0f)));
        c = guardf(fmaf(aa2, frcp(c), 1.0f));
        float del = d * c;
        h *= del;
        if (__all(fabsf(del - 1.0f) < EPS)) break;
    }
    return h;
}

// ---------------------------------------------------------------------------
// Stage 2: one block (4 waves) per pair. Waves 0-3 chunk-reduce partials and
// compute x for 128 h each; wave 0 then does top-d (monotonicity: top-d of
// betainc == top-d of x) + d CF evals + last-block writeout.
// ---------------------------------------------------------------------------
__global__ __launch_bounds__(256) void stage2_kernel(
    const float* __restrict__ part_m, const float* __restrict__ part_s,
    const float* __restrict__ pcol, float* __restrict__ ctl,
    const int* __restrict__ dptr, float* __restrict__ out)
{
    __shared__ float xs[HH];

    const int t = threadIdx.x;
    const int w = t >> 6, lane = t & 63;
    const int p = blockIdx.x;

    int i = 0, rem = p;
    while (true) { int row = KK - 1 - i; if (rem < row) break; rem -= row; ++i; }
    const int j = i + 1 + rem;

    float ci = 0.f, cj = 0.f;
#pragma unroll
    for (int cc = 0; cc < NBB; ++cc) {
        ci += pcol[cc * KK + i];
        cj += pcol[cc * KK + j];
    }
    ci = roundf(ci); cj = roundf(cj);
    const float pc = ci + cj;
    float d2 = pc - 2.0f;
    if (d2 == 0.0f) d2 = 1e-5f;
    const float a = 0.5f;
    const float b = 0.5f * d2;

#pragma unroll
    for (int q = 0; q < 2; ++q) {
        int h = w * 128 + q * 64 + lane;
        float mi = 0.f, mj = 0.f, si = 0.f, sj = 0.f;
#pragma unroll
        for (int cc = 0; cc < NBB; ++cc) {
            size_t base = (size_t)cc * KK * HH;
            mi += part_m[base + (size_t)i * HH + h];
            mj += part_m[base + (size_t)j * HH + h];
            si += part_s[base + (size_t)i * HH + h];
            sj += part_s[base + (size_t)j * HH + h];
        }
        float wi = fmaf((float)(BB - 2) * mi, mi, si);
        float wj = fmaf((float)(BB - 2) * mj, mj, sj);
        float dm = 0.5f * (mi - mj);
        float between = dm * dm * pc;
        float denom = between + wi + wj;
        float x = between / denom;
        if (!(x >= 1e-37f)) x = 1e-37f;       // also catches NaN
        x = fminf(x, 1.0f - 1e-5f);
        xs[h] = x;
    }
    __syncthreads();
    if (w != 0) return;

    // ---- wave 0: top-d selection over 512 x values (8/lane) ----
    float lv[8];
#pragma unroll
    for (int q = 0; q < 8; ++q) lv[q] = xs[q * 64 + lane];

    const int d = *dptr;
    const float lg = lgammaf(a + b) - lgammaf(b) - 0.57236494f;
    const float xsplit = (a + 1.0f) / (a + b + 2.0f);

    float myx = 0.004f;
    float lm = lv[0];
#pragma unroll
    for (int q = 1; q < 8; ++q) lm = fmaxf(lm, lv[q]);

    for (int r = 0; r < d; ++r) {
        float gm = lm;
#pragma unroll
        for (int off = 1; off < 64; off <<= 1)
            gm = fmaxf(gm, __shfl_xor(gm, off));
        unsigned long long msk = __ballot(lm == gm);
        int winner = __ffsll((unsigned long long)msk) - 1;
        if (lane == r) myx = gm;
        if (lane == winner) {
            bool done = false;
#pragma unroll
            for (int q = 0; q < 8; ++q)
                if (!done && lv[q] == gm) { lv[q] = -1.0f; done = true; }
            lm = lv[0];
#pragma unroll
            for (int q = 1; q < 8; ++q) lm = fmaxf(lm, lv[q]);
        }
    }

    // ---- d parallel betainc evals ----
    float x   = myx;
    float omx = 1.0f - x;
    bool  brA = x < xsplit;
    float al  = brA ? a : b;
    float be  = brA ? b : a;
    float xx  = brA ? x : omx;
    float cf  = betacf_fast(al, be, xx);
    float lbt = lg + 0.5f * logf(x) + b * logf(omx);
    float L;
    if (brA) {
        L = lbt + logf(2.0f * fmaxf(cf, 1e-30f));
    } else {
        float tt = expf(lbt) * cf / b;
        tt = fminf(tt, 0.99999988f);
        L = log1pf(-tt);
    }

    float val = (lane < d) ? L : 0.0f;
#pragma unroll
    for (int off = 1; off < 64; off <<= 1) val += __shfl_xor(val, off);

    if (lane == 0) {
        atomicAdd(&ctl[0], -val);
        __threadfence();
        unsigned old = atomicAdd((unsigned*)ctl + 1, 1u);
        if (old == PAIRS - 1) {
            out[0] = atomicAdd(&ctl[0], 0.0f);   // atomic read of final sum
        }
    }
}

// ---------------------------------------------------------------------------
extern "C" void kernel_launch(void* const* d_in, const int* in_sizes, int n_in,
                              void* d_out, int out_size, void* d_ws, size_t ws_size,
                              hipStream_t stream)
{
    const float* hidden  = (const float*)d_in[0];
    const float* cluster = (const float*)d_in[1];
    const int*   dptr    = (const int*)d_in[2];

    float* part_m = (float*)d_ws;                    // [NBB][KK][HH]
    float* part_s = part_m + (size_t)NBB * KK * HH;  // [NBB][KK][HH]
    float* pcol   = part_s + (size_t)NBB * KK * HH;  // [NBB][KK]
    float* ctl    = pcol + NBB * KK;                 // accum, counter

    dim3 g1(HH / TH, NBB);
    stage1_kernel<<<g1, 256, 0, stream>>>(hidden, cluster,
                                          part_m, part_s, pcol, ctl);
    stage2_kernel<<<PAIRS, 256, 0, stream>>>(part_m, part_s, pcol, ctl,
                                             dptr, (float*)d_out);
}